// Round 7
// baseline (170.931 us; speedup 1.0000x reference)
//
#include <hip/hip_runtime.h>

#define C 32
#define BSH 8
#define BNODE 256
#define CAPC 5632          // per-bucket capacity (mean 4096, wide margin)
#define SRCMASK 0x1FFFF

typedef float f32x4 __attribute__((ext_vector_type(4)));
typedef float f32x2 __attribute__((ext_vector_type(2)));

__device__ __forceinline__ unsigned int f2bf(float f) {
    unsigned int u = __float_as_uint(f);
    return (u + 0x7FFFu + ((u >> 16) & 1u)) >> 16;   // RNE to bf16
}
__device__ __forceinline__ float bflo(unsigned int u) { return __uint_as_float(u << 16); }
__device__ __forceinline__ float bfhi(unsigned int u) { return __uint_as_float(u & 0xFFFF0000u); }

// Phase A (verified): bucketize by dst>>8 via LDS hist + per-bucket global
// reservation; x -> bf16 conversion into TWO channel-half tables.
__global__ __launch_bounds__(1024) void phaseA_cvt(const int* __restrict__ src,
                                                   const int* __restrict__ dst,
                                                   int* __restrict__ cursor,
                                                   int* __restrict__ pk,
                                                   const float* __restrict__ x,
                                                   unsigned int* __restrict__ xbh,
                                                   int N, int E, int nbuck, int chunk) {
    extern __shared__ int l[];          // lcnt[nbuck] | lcur[nbuck]
    int* lcnt = l;
    int* lcur = l + nbuck;
    int tid = threadIdx.x;
    for (int i = tid; i < nbuck; i += 1024) lcnt[i] = 0;
    __syncthreads();
    int base = blockIdx.x * chunk;
    int end  = min(base + chunk, E);
    for (int e = base + tid; e < end; e += 1024)
        atomicAdd(&lcnt[dst[e] >> BSH], 1);
    __syncthreads();
    for (int i = tid; i < nbuck; i += 1024) {
        int c = lcnt[i];
        lcur[i] = i * CAPC + (c ? atomicAdd(&cursor[i], c) : 0);
    }
    __syncthreads();
    for (int e = base + tid; e < end; e += 1024) {
        int d = dst[e];
        int b = d >> BSH;
        int pos = atomicAdd(&lcur[b], 1);
        pk[pos] = src[e] | ((d & (BNODE - 1)) << 17);
    }
    int total = N * 8;
    int gid = blockIdx.x * 1024 + tid;
    int gth = gridDim.x * 1024;
    for (int i = gid; i < total; i += gth) {
        f32x4 v = *(const f32x4*)(x + (size_t)i * 4);
        uint2 r;
        r.x = f2bf(v.x) | (f2bf(v.y) << 16);
        r.y = f2bf(v.z) | (f2bf(v.w) << 16);
        int node = i >> 3;
        int q = i & 7;
        int half = q >> 2;
        ((uint2*)xbh)[((size_t)half * N + node) * 4 + (q & 3)] = r;
    }
}

// One masked 8-wide gather round over idx[j..hi): clamped indices, ?:-zeroed
// lanes. Any tail costs exactly ONE latency round (old 4-deep+scalar cascade
// averaged ~2 extra serial rounds per Poisson(16) walk).
__device__ __forceinline__ void round8m(const unsigned int* __restrict__ tab,
                                        const int* idx, int j, int hi, int lq,
                                        float& a0, float& a1) {
    int e = hi - 1;
    int s0 = idx[j];
    int s1 = idx[min(j + 1, e)];
    int s2 = idx[min(j + 2, e)];
    int s3 = idx[min(j + 3, e)];
    int s4 = idx[min(j + 4, e)];
    int s5 = idx[min(j + 5, e)];
    int s6 = idx[min(j + 6, e)];
    int s7 = idx[min(j + 7, e)];
    unsigned int u0 = tab[(size_t)s0 * 8 + lq];
    unsigned int u1 = tab[(size_t)s1 * 8 + lq];
    unsigned int u2 = tab[(size_t)s2 * 8 + lq];
    unsigned int u3 = tab[(size_t)s3 * 8 + lq];
    unsigned int u4 = tab[(size_t)s4 * 8 + lq];
    unsigned int u5 = tab[(size_t)s5 * 8 + lq];
    unsigned int u6 = tab[(size_t)s6 * 8 + lq];
    unsigned int u7 = tab[(size_t)s7 * 8 + lq];
    u1 = (j + 1 <= e) ? u1 : 0u;
    u2 = (j + 2 <= e) ? u2 : 0u;
    u3 = (j + 3 <= e) ? u3 : 0u;
    u4 = (j + 4 <= e) ? u4 : 0u;
    u5 = (j + 5 <= e) ? u5 : 0u;
    u6 = (j + 6 <= e) ? u6 : 0u;
    u7 = (j + 7 <= e) ? u7 : 0u;
    a0 += bflo(u0); a1 += bfhi(u0);
    a0 += bflo(u1); a1 += bfhi(u1);
    a0 += bflo(u2); a1 += bfhi(u2);
    a0 += bflo(u3); a1 += bfhi(u3);
    a0 += bflo(u4); a1 += bfhi(u4);
    a0 += bflo(u5); a1 += bfhi(u5);
    a0 += bflo(u6); a1 += bfhi(u6);
    a0 += bflo(u7); a1 += bfhi(u7);
}

// Walk two independent segments interleaved: A's and B's 8-batches are issued
// back-to-back before either accumulates -> up to 16 loads in flight/thread.
__device__ __forceinline__ void walk2(const unsigned int* __restrict__ tab,
                                      const int* idx,
                                      int loA, int hiA, int loB, int hiB, int lq,
                                      float& a0A, float& a1A,
                                      float& a0B, float& a1B) {
    int jA = loA, jB = loB;
    while (jA < hiA && jB < hiB) {
        round8m(tab, idx, jA, hiA, lq, a0A, a1A);
        round8m(tab, idx, jB, hiB, lq, a0B, a1B);
        jA += 8; jB += 8;
    }
    for (; jA < hiA; jA += 8) round8m(tab, idx, jA, hiA, lq, a0A, a1A);
    for (; jB < hiB; jB += 8) round8m(tab, idx, jB, hiB, lq, a0B, a1B);
}

// Phase B + matvec1: counting sort in LDS (verified), coalesced pk write-back,
// then t1 = bf16(deg*x - A@x) in two channel-half passes; each thread owns
// two nodes (rA, rA+128) walked interleaved.
__global__ __launch_bounds__(1024) void phaseB_mv1(int* __restrict__ pk,
                                                   const int* __restrict__ cursor,
                                                   int* __restrict__ row_start,
                                                   int* __restrict__ ideg,
                                                   const unsigned int* __restrict__ xbh,
                                                   unsigned int* __restrict__ t1h, int N) {
    __shared__ int ent[CAPC];
    __shared__ int sorted[CAPC];
    __shared__ int h[BNODE];
    __shared__ int ss[BNODE];
    __shared__ int cur[BNODE];
    int b = blockIdx.x;
    int tid = threadIdx.x;
    int n0 = b << BSH;
    int base = b * CAPC;
    int cnt = min(cursor[b], CAPC);

    if (tid < BNODE) h[tid] = 0;
    __syncthreads();
    for (int i = tid; i < cnt; i += 1024) {
        int en = __builtin_nontemporal_load(&pk[base + i]);
        ent[i] = en;
        atomicAdd(&h[en >> 17], 1);
    }
    __syncthreads();
    int v = 0;
    if (tid < BNODE) { v = h[tid]; ss[tid] = v; }
    __syncthreads();
    for (int off = 1; off < BNODE; off <<= 1) {
        int u = 0;
        if (tid < BNODE && tid >= off) u = ss[tid - off];
        __syncthreads();
        if (tid < BNODE) ss[tid] += u;
        __syncthreads();
    }
    if (tid < BNODE) {
        int exc = ss[tid] - v;
        int n = n0 + tid;
        if (n < N) { row_start[n] = base + exc; ideg[n] = v; }
        cur[tid] = exc;
    }
    __syncthreads();
    for (int i = tid; i < cnt; i += 1024) {
        int en = ent[i];
        int pos = atomicAdd(&cur[en >> 17], 1);
        sorted[pos] = en & SRCMASK;
    }
    __syncthreads();
    for (int i = tid; i < cnt; i += 1024)          // coalesced write-back
        pk[base + i] = sorted[i];

    // ---- matvec1, two channel-half passes, 2-node interleaved walks ----
    int lq = tid & 7;
    int rA = tid >> 3;                 // 0..127
    int rB = rA + 128;                 // 128..255
    int hiA = ss[rA], loA = hiA - h[rA];
    int hiB = ss[rB], loB = hiB - h[rB];
    int nA = n0 + rA;
    int nB = n0 + rB;
    for (int hf = 0; hf < 2; ++hf) {
        const unsigned int* tab = xbh + (size_t)hf * N * 8;
        unsigned int* ttab = t1h + (size_t)hf * N * 8;
        float a0A = 0.f, a1A = 0.f, a0B = 0.f, a1B = 0.f;
        walk2(tab, sorted, loA, hiA, loB, hiB, lq, a0A, a1A, a0B, a1B);
        if (nA < N) {
            unsigned int xs = tab[(size_t)nA * 8 + lq];
            float fdg = (float)h[rA];
            ttab[(size_t)nA * 8 + lq] = f2bf(fdg * bflo(xs) - a0A)
                                      | (f2bf(fdg * bfhi(xs) - a1A) << 16);
        }
        if (nB < N) {
            unsigned int xs = tab[(size_t)nB * 8 + lq];
            float fdg = (float)h[rB];
            ttab[(size_t)nB * 8 + lq] = f2bf(fdg * bflo(xs) - a0B)
                                      | (f2bf(fdg * bfhi(xs) - a1B) << 16);
        }
    }
}

// gather2: stage sorted pk into LDS (coalesced), then
// y = w0*x + w1*t1 + w2*(deg*t1 - A@t1), 2-node interleaved walks per thread.
__global__ __launch_bounds__(1024) void gather2_lds(const unsigned int* __restrict__ xbh,
        const unsigned int* __restrict__ t1h, const int* __restrict__ pk,
        const int* __restrict__ cursor, const int* __restrict__ row_start,
        const int* __restrict__ ideg, const float* __restrict__ wts,
        float* __restrict__ y, int N) {
    __shared__ int stg[CAPC];
    int b = blockIdx.x;
    int tid = threadIdx.x;
    int n0 = b << BSH;
    int base = b * CAPC;
    int cnt = min(cursor[b], CAPC);
    for (int i = tid; i < cnt; i += 1024)
        stg[i] = __builtin_nontemporal_load(&pk[base + i]);
    __syncthreads();
    float w0 = wts[0], w1 = wts[1], w2 = wts[2];
    int lq = tid & 7;
    int rA = tid >> 3;
    int rB = rA + 128;
    int nA = n0 + rA;
    int nB = n0 + rB;
    int dgA = 0, loA = 0;
    if (nA < N) { dgA = ideg[nA]; loA = row_start[nA] - base; }
    int hiA = loA + dgA;
    int dgB = 0, loB = 0;
    if (nB < N) { dgB = ideg[nB]; loB = row_start[nB] - base; }
    int hiB = loB + dgB;
    for (int hf = 0; hf < 2; ++hf) {
        const unsigned int* xtab = xbh + (size_t)hf * N * 8;
        const unsigned int* ttab = t1h + (size_t)hf * N * 8;
        float a0A = 0.f, a1A = 0.f, a0B = 0.f, a1B = 0.f;
        walk2(ttab, stg, loA, hiA, loB, hiB, lq, a0A, a1A, a0B, a1B);
        if (nA < N) {
            unsigned int xs = xtab[(size_t)nA * 8 + lq];
            unsigned int ts = ttab[(size_t)nA * 8 + lq];
            float fdg = (float)dgA;
            f32x2 yv;
            yv.x = w0 * bflo(xs) + w1 * bflo(ts) + w2 * (fdg * bflo(ts) - a0A);
            yv.y = w0 * bfhi(xs) + w1 * bfhi(ts) + w2 * (fdg * bfhi(ts) - a1A);
            __builtin_nontemporal_store(yv,
                (f32x2*)(y + (size_t)nA * C + hf * 16 + lq * 2));
        }
        if (nB < N) {
            unsigned int xs = xtab[(size_t)nB * 8 + lq];
            unsigned int ts = ttab[(size_t)nB * 8 + lq];
            float fdg = (float)dgB;
            f32x2 yv;
            yv.x = w0 * bflo(xs) + w1 * bflo(ts) + w2 * (fdg * bflo(ts) - a0B);
            yv.y = w0 * bfhi(xs) + w1 * bfhi(ts) + w2 * (fdg * bfhi(ts) - a1B);
            __builtin_nontemporal_store(yv,
                (f32x2*)(y + (size_t)nB * C + hf * 16 + lq * 2));
        }
    }
}

extern "C" void kernel_launch(void* const* d_in, const int* in_sizes, int n_in,
                              void* d_out, int out_size, void* d_ws, size_t ws_size,
                              hipStream_t stream) {
    const float* x    = (const float*)d_in[0];
    const float* wts  = (const float*)d_in[1];
    const int*   esrc = (const int*)d_in[2];
    const int*   edst = (const int*)d_in[3];
    float*       y    = (float*)d_out;

    const int N = in_sizes[0] / C;                 // 100000
    const int E = in_sizes[2];                     // 1600000
    const int nbuck = (N + BNODE - 1) >> BSH;      // 391
    const int nc = N * C;

    char* p = (char*)d_ws;
    auto align16 = [](size_t s) { return (s + 15) & ~(size_t)15; };
    int* cursor    = (int*)p; p += align16((size_t)nbuck * 4);
    int* row_start = (int*)p; p += align16((size_t)N * 4);
    int* ideg      = (int*)p; p += align16((size_t)N * 4);
    int* pk        = (int*)p; p += align16((size_t)nbuck * CAPC * 4);
    unsigned int* xbh = (unsigned int*)p; p += align16((size_t)nc * 2);  // 2 half-tables
    unsigned int* t1h = (unsigned int*)p; p += align16((size_t)nc * 2);
    (void)ws_size;

    (void)hipMemsetAsync(cursor, 0, (size_t)nbuck * 4, stream);

    const int ABLK = 512;
    const int chunk = (E + ABLK - 1) / ABLK;
    const size_t lds_a = (size_t)nbuck * 2 * 4;

    phaseA_cvt<<<ABLK, 1024, lds_a, stream>>>(esrc, edst, cursor, pk, x, xbh,
                                              N, E, nbuck, chunk);
    phaseB_mv1<<<nbuck, 1024, 0, stream>>>(pk, cursor, row_start, ideg,
                                           xbh, t1h, N);
    gather2_lds<<<nbuck, 1024, 0, stream>>>(xbh, t1h, pk, cursor, row_start,
                                            ideg, wts, y, N);
}

// Round 8
// 164.201 us; speedup vs baseline: 1.0410x; 1.0410x over previous
//
#include <hip/hip_runtime.h>

#define C 32
#define BSH 8
#define BNODE 256
#define CAPC 5632          // per-bucket capacity (mean 4096, wide margin)
#define SRCMASK 0x1FFFF

typedef float f32x4 __attribute__((ext_vector_type(4)));
typedef float f32x2 __attribute__((ext_vector_type(2)));

__device__ __forceinline__ unsigned int f2bf(float f) {
    unsigned int u = __float_as_uint(f);
    return (u + 0x7FFFu + ((u >> 16) & 1u)) >> 16;   // RNE to bf16
}
__device__ __forceinline__ float bflo(unsigned int u) { return __uint_as_float(u << 16); }
__device__ __forceinline__ float bfhi(unsigned int u) { return __uint_as_float(u & 0xFFFF0000u); }

// Phase A: bucketize by dst>>8 via LDS hist + per-bucket global reservation.
// Edges are read ONCE: each thread holds its <=4 (src,dst) pairs in named
// registers (static indexing) across hist -> reserve -> scatter. Fused
// x -> bf16 conversion into TWO channel-half tables (3.2MB each).
__global__ __launch_bounds__(1024) void phaseA_cvt(const int* __restrict__ src,
                                                   const int* __restrict__ dst,
                                                   int* __restrict__ cursor,
                                                   int* __restrict__ pk,
                                                   const float* __restrict__ x,
                                                   unsigned int* __restrict__ xbh,
                                                   int N, int E, int nbuck, int chunk) {
    extern __shared__ int l[];          // lcnt[nbuck] | lcur[nbuck]
    int* lcnt = l;
    int* lcur = l + nbuck;
    int tid = threadIdx.x;
    for (int i = tid; i < nbuck; i += 1024) lcnt[i] = 0;
    __syncthreads();
    int base = blockIdx.x * chunk;
    int end  = min(base + chunk, E);
    int e0 = base + tid, e1 = e0 + 1024, e2 = e0 + 2048, e3 = e0 + 3072;
    int s0 = 0, s1 = 0, s2 = 0, s3 = 0, d0 = 0, d1 = 0, d2 = 0, d3 = 0;
    if (e0 < end) { s0 = src[e0]; d0 = dst[e0]; atomicAdd(&lcnt[d0 >> BSH], 1); }
    if (e1 < end) { s1 = src[e1]; d1 = dst[e1]; atomicAdd(&lcnt[d1 >> BSH], 1); }
    if (e2 < end) { s2 = src[e2]; d2 = dst[e2]; atomicAdd(&lcnt[d2 >> BSH], 1); }
    if (e3 < end) { s3 = src[e3]; d3 = dst[e3]; atomicAdd(&lcnt[d3 >> BSH], 1); }
    for (int e = e3 + 1024; e < end; e += 1024)      // safety (chunk > 4096)
        atomicAdd(&lcnt[dst[e] >> BSH], 1);
    __syncthreads();
    for (int i = tid; i < nbuck; i += 1024) {
        int c = lcnt[i];
        lcur[i] = i * CAPC + (c ? atomicAdd(&cursor[i], c) : 0);
    }
    __syncthreads();
    if (e0 < end) { int p_ = atomicAdd(&lcur[d0 >> BSH], 1); pk[p_] = s0 | ((d0 & (BNODE - 1)) << 17); }
    if (e1 < end) { int p_ = atomicAdd(&lcur[d1 >> BSH], 1); pk[p_] = s1 | ((d1 & (BNODE - 1)) << 17); }
    if (e2 < end) { int p_ = atomicAdd(&lcur[d2 >> BSH], 1); pk[p_] = s2 | ((d2 & (BNODE - 1)) << 17); }
    if (e3 < end) { int p_ = atomicAdd(&lcur[d3 >> BSH], 1); pk[p_] = s3 | ((d3 & (BNODE - 1)) << 17); }
    for (int e = e3 + 1024; e < end; e += 1024) {    // safety (chunk > 4096)
        int d = dst[e];
        int p_ = atomicAdd(&lcur[d >> BSH], 1);
        pk[p_] = src[e] | ((d & (BNODE - 1)) << 17);
    }
    int total = N * 8;
    int gid = blockIdx.x * 1024 + tid;
    int gth = gridDim.x * 1024;
    for (int i = gid; i < total; i += gth) {
        f32x4 v = *(const f32x4*)(x + (size_t)i * 4);
        uint2 r;
        r.x = f2bf(v.x) | (f2bf(v.y) << 16);
        r.y = f2bf(v.z) | (f2bf(v.w) << 16);
        int node = i >> 3;
        int q = i & 7;
        int half = q >> 2;
        ((uint2*)xbh)[((size_t)half * N + node) * 4 + (q & 3)] = r;
    }
}

// packed accumulate of one bf16x2 word into an f32x2 accumulator
// ({lo,hi} built, then one vector add -> v_pk_add_f32 candidate)
__device__ __forceinline__ void acc_pk(f32x2& a, unsigned int u) {
    f32x2 t;
    t.x = bflo(u);
    t.y = bfhi(u);
    a += t;
}

// accumulate one half-table (2 channels per lane) over LDS indices
// idx[lo..hi). Main loop: clean unmasked 8-deep unroll (8 lines in flight).
// Tail (<=7): ONE masked round instead of a 4-deep + scalar cascade.
__device__ __forceinline__ f32x2 accum_h(const unsigned int* __restrict__ tab,
                                         const int* idx, int lo, int hi, int lq) {
    f32x2 a = {0.f, 0.f};
    int j = lo;
    for (; j + 7 < hi; j += 8) {
        int s0 = idx[j],     s1 = idx[j + 1], s2 = idx[j + 2], s3 = idx[j + 3];
        int s4 = idx[j + 4], s5 = idx[j + 5], s6 = idx[j + 6], s7 = idx[j + 7];
        unsigned int u0 = tab[(size_t)s0 * 8 + lq];
        unsigned int u1 = tab[(size_t)s1 * 8 + lq];
        unsigned int u2 = tab[(size_t)s2 * 8 + lq];
        unsigned int u3 = tab[(size_t)s3 * 8 + lq];
        unsigned int u4 = tab[(size_t)s4 * 8 + lq];
        unsigned int u5 = tab[(size_t)s5 * 8 + lq];
        unsigned int u6 = tab[(size_t)s6 * 8 + lq];
        unsigned int u7 = tab[(size_t)s7 * 8 + lq];
        acc_pk(a, u0); acc_pk(a, u1); acc_pk(a, u2); acc_pk(a, u3);
        acc_pk(a, u4); acc_pk(a, u5); acc_pk(a, u6); acc_pk(a, u7);
    }
    if (j < hi) {                      // masked single-round tail (1..7 entries)
        int e = hi - 1;
        int s0 = idx[j];
        int s1 = idx[min(j + 1, e)];
        int s2 = idx[min(j + 2, e)];
        int s3 = idx[min(j + 3, e)];
        int s4 = idx[min(j + 4, e)];
        int s5 = idx[min(j + 5, e)];
        int s6 = idx[min(j + 6, e)];
        int s7 = idx[min(j + 7, e)];
        unsigned int u0 = tab[(size_t)s0 * 8 + lq];
        unsigned int u1 = tab[(size_t)s1 * 8 + lq];
        unsigned int u2 = tab[(size_t)s2 * 8 + lq];
        unsigned int u3 = tab[(size_t)s3 * 8 + lq];
        unsigned int u4 = tab[(size_t)s4 * 8 + lq];
        unsigned int u5 = tab[(size_t)s5 * 8 + lq];
        unsigned int u6 = tab[(size_t)s6 * 8 + lq];
        unsigned int u7 = tab[(size_t)s7 * 8 + lq];
        u1 = (j + 1 <= e) ? u1 : 0u;
        u2 = (j + 2 <= e) ? u2 : 0u;
        u3 = (j + 3 <= e) ? u3 : 0u;
        u4 = (j + 4 <= e) ? u4 : 0u;
        u5 = (j + 5 <= e) ? u5 : 0u;
        u6 = (j + 6 <= e) ? u6 : 0u;
        u7 = (j + 7 <= e) ? u7 : 0u;
        acc_pk(a, u0); acc_pk(a, u1); acc_pk(a, u2); acc_pk(a, u3);
        acc_pk(a, u4); acc_pk(a, u5); acc_pk(a, u6); acc_pk(a, u7);
    }
    return a;
}

// Phase B + matvec1: per-bucket counting sort in LDS, coalesced pk write-back,
// then t1 = bf16(deg*x - A@x) in two channel-half passes, indices from LDS.
__global__ __launch_bounds__(1024) void phaseB_mv1(int* __restrict__ pk,
                                                   const int* __restrict__ cursor,
                                                   int* __restrict__ row_start,
                                                   int* __restrict__ ideg,
                                                   const unsigned int* __restrict__ xbh,
                                                   unsigned int* __restrict__ t1h, int N) {
    __shared__ int ent[CAPC];
    __shared__ int sorted[CAPC];
    __shared__ int h[BNODE];
    __shared__ int ss[BNODE];
    __shared__ int cur[BNODE];
    int b = blockIdx.x;
    int tid = threadIdx.x;
    int n0 = b << BSH;
    int base = b * CAPC;
    int cnt = min(cursor[b], CAPC);

    if (tid < BNODE) h[tid] = 0;
    __syncthreads();
    for (int i = tid; i < cnt; i += 1024) {
        int en = __builtin_nontemporal_load(&pk[base + i]);
        ent[i] = en;
        atomicAdd(&h[en >> 17], 1);
    }
    __syncthreads();
    int v = 0;
    if (tid < BNODE) { v = h[tid]; ss[tid] = v; }
    __syncthreads();
    for (int off = 1; off < BNODE; off <<= 1) {
        int u = 0;
        if (tid < BNODE && tid >= off) u = ss[tid - off];
        __syncthreads();
        if (tid < BNODE) ss[tid] += u;
        __syncthreads();
    }
    if (tid < BNODE) {
        int exc = ss[tid] - v;
        int n = n0 + tid;
        if (n < N) { row_start[n] = base + exc; ideg[n] = v; }
        cur[tid] = exc;
    }
    __syncthreads();
    for (int i = tid; i < cnt; i += 1024) {
        int en = ent[i];
        int pos = atomicAdd(&cur[en >> 17], 1);
        sorted[pos] = en & SRCMASK;
    }
    __syncthreads();
    for (int i = tid; i < cnt; i += 1024)          // coalesced write-back
        pk[base + i] = sorted[i];

    // ---- matvec1, two channel-half passes ----
    for (int hf = 0; hf < 2; ++hf) {
        const unsigned int* tab = xbh + (size_t)hf * N * 8;
        unsigned int* ttab = t1h + (size_t)hf * N * 8;
        for (int it = tid; it < BNODE * 8; it += 1024) {
            int r = it >> 3;
            int lq = it & 7;
            int n = n0 + r;
            if (n >= N) continue;
            int hi = ss[r];
            int lo = hi - h[r];
            f32x2 a = accum_h(tab, sorted, lo, hi, lq);
            unsigned int xs = tab[(size_t)n * 8 + lq];
            float fdg = (float)h[r];
            unsigned int rr = f2bf(fdg * bflo(xs) - a.x)
                            | (f2bf(fdg * bfhi(xs) - a.y) << 16);
            ttab[(size_t)n * 8 + lq] = rr;   // regular store: stay L2-resident
        }
    }
}

// gather2: stage sorted pk into LDS (coalesced), then
// y = w0*x + w1*t1 + w2*(deg*t1 - A@t1) in two channel-half passes.
__global__ __launch_bounds__(1024) void gather2_lds(const unsigned int* __restrict__ xbh,
        const unsigned int* __restrict__ t1h, const int* __restrict__ pk,
        const int* __restrict__ cursor, const int* __restrict__ row_start,
        const int* __restrict__ ideg, const float* __restrict__ wts,
        float* __restrict__ y, int N) {
    __shared__ int stg[CAPC];
    int b = blockIdx.x;
    int tid = threadIdx.x;
    int n0 = b << BSH;
    int base = b * CAPC;
    int cnt = min(cursor[b], CAPC);
    for (int i = tid; i < cnt; i += 1024)
        stg[i] = __builtin_nontemporal_load(&pk[base + i]);
    __syncthreads();
    float w0 = wts[0], w1 = wts[1], w2 = wts[2];
    for (int hf = 0; hf < 2; ++hf) {
        const unsigned int* xtab = xbh + (size_t)hf * N * 8;
        const unsigned int* ttab = t1h + (size_t)hf * N * 8;
        for (int it = tid; it < BNODE * 8; it += 1024) {
            int r = it >> 3;
            int lq = it & 7;
            int n = n0 + r;
            if (n >= N) continue;
            int dg = ideg[n];
            int lo = row_start[n] - base;      // local offset in stg
            int hi = lo + dg;
            f32x2 a = accum_h(ttab, stg, lo, hi, lq);
            unsigned int xs = xtab[(size_t)n * 8 + lq];
            unsigned int ts = ttab[(size_t)n * 8 + lq];
            float fdg = (float)dg;
            f32x2 yv;
            yv.x = w0 * bflo(xs) + w1 * bflo(ts) + w2 * (fdg * bflo(ts) - a.x);
            yv.y = w0 * bfhi(xs) + w1 * bfhi(ts) + w2 * (fdg * bfhi(ts) - a.y);
            __builtin_nontemporal_store(yv,
                (f32x2*)(y + (size_t)n * C + hf * 16 + lq * 2));
        }
    }
}

extern "C" void kernel_launch(void* const* d_in, const int* in_sizes, int n_in,
                              void* d_out, int out_size, void* d_ws, size_t ws_size,
                              hipStream_t stream) {
    const float* x    = (const float*)d_in[0];
    const float* wts  = (const float*)d_in[1];
    const int*   esrc = (const int*)d_in[2];
    const int*   edst = (const int*)d_in[3];
    float*       y    = (float*)d_out;

    const int N = in_sizes[0] / C;                 // 100000
    const int E = in_sizes[2];                     // 1600000
    const int nbuck = (N + BNODE - 1) >> BSH;      // 391
    const int nc = N * C;

    char* p = (char*)d_ws;
    auto align16 = [](size_t s) { return (s + 15) & ~(size_t)15; };
    int* cursor    = (int*)p; p += align16((size_t)nbuck * 4);
    int* row_start = (int*)p; p += align16((size_t)N * 4);
    int* ideg      = (int*)p; p += align16((size_t)N * 4);
    int* pk        = (int*)p; p += align16((size_t)nbuck * CAPC * 4);
    unsigned int* xbh = (unsigned int*)p; p += align16((size_t)nc * 2);  // 2 half-tables
    unsigned int* t1h = (unsigned int*)p; p += align16((size_t)nc * 2);
    (void)ws_size;

    (void)hipMemsetAsync(cursor, 0, (size_t)nbuck * 4, stream);

    const int ABLK = 512;
    const int chunk = (E + ABLK - 1) / ABLK;
    const size_t lds_a = (size_t)nbuck * 2 * 4;

    phaseA_cvt<<<ABLK, 1024, lds_a, stream>>>(esrc, edst, cursor, pk, x, xbh,
                                              N, E, nbuck, chunk);
    phaseB_mv1<<<nbuck, 1024, 0, stream>>>(pk, cursor, row_start, ideg,
                                           xbh, t1h, N);
    gather2_lds<<<nbuck, 1024, 0, stream>>>(xbh, t1h, pk, cursor, row_start,
                                            ideg, wts, y, N);
}

// Round 9
// 161.360 us; speedup vs baseline: 1.0593x; 1.0176x over previous
//
#include <hip/hip_runtime.h>

#define C 32
#define BSH 7
#define BNODE 128
#define CAPC 2816          // per-bucket capacity (mean 2048, sigma~45, +17 sigma)
#define NTB 512            // threads per phaseB/gather2 block (4 blocks/CU co-resident)
#define SRCMASK 0x1FFFF

typedef float f32x4 __attribute__((ext_vector_type(4)));
typedef float f32x2 __attribute__((ext_vector_type(2)));

__device__ __forceinline__ unsigned int f2bf(float f) {
    unsigned int u = __float_as_uint(f);
    return (u + 0x7FFFu + ((u >> 16) & 1u)) >> 16;   // RNE to bf16
}
__device__ __forceinline__ float bflo(unsigned int u) { return __uint_as_float(u << 16); }
__device__ __forceinline__ float bfhi(unsigned int u) { return __uint_as_float(u & 0xFFFF0000u); }

// Phase A (R6-verified): bucketize by dst>>7 via LDS hist + per-bucket global
// reservation; x -> bf16 conversion into TWO channel-half tables (3.2MB each).
__global__ __launch_bounds__(1024) void phaseA_cvt(const int* __restrict__ src,
                                                   const int* __restrict__ dst,
                                                   int* __restrict__ cursor,
                                                   int* __restrict__ pk,
                                                   const float* __restrict__ x,
                                                   unsigned int* __restrict__ xbh,
                                                   int N, int E, int nbuck, int chunk) {
    extern __shared__ int l[];          // lcnt[nbuck] | lcur[nbuck]
    int* lcnt = l;
    int* lcur = l + nbuck;
    int tid = threadIdx.x;
    for (int i = tid; i < nbuck; i += 1024) lcnt[i] = 0;
    __syncthreads();
    int base = blockIdx.x * chunk;
    int end  = min(base + chunk, E);
    for (int e = base + tid; e < end; e += 1024)
        atomicAdd(&lcnt[dst[e] >> BSH], 1);
    __syncthreads();
    for (int i = tid; i < nbuck; i += 1024) {
        int c = lcnt[i];
        lcur[i] = i * CAPC + (c ? atomicAdd(&cursor[i], c) : 0);
    }
    __syncthreads();
    for (int e = base + tid; e < end; e += 1024) {
        int d = dst[e];
        int b = d >> BSH;
        int pos = atomicAdd(&lcur[b], 1);
        pk[pos] = src[e] | ((d & (BNODE - 1)) << 17);
    }
    int total = N * 8;
    int gid = blockIdx.x * 1024 + tid;
    int gth = gridDim.x * 1024;
    for (int i = gid; i < total; i += gth) {
        f32x4 v = *(const f32x4*)(x + (size_t)i * 4);
        uint2 r;
        r.x = f2bf(v.x) | (f2bf(v.y) << 16);
        r.y = f2bf(v.z) | (f2bf(v.w) << 16);
        int node = i >> 3;
        int q = i & 7;
        int half = q >> 2;
        ((uint2*)xbh)[((size_t)half * N + node) * 4 + (q & 3)] = r;
    }
}

// accumulate one half-table (2 channels per lane) over LDS indices idx[lo..hi).
// 8-deep unroll (R6-verified): 8 independent 32B-line gathers in flight.
__device__ __forceinline__ void accum_h(const unsigned int* __restrict__ tab,
                                        const int* idx, int lo, int hi, int lq,
                                        float& a0, float& a1) {
#define ACC2(u) { a0 += bflo(u); a1 += bfhi(u); }
    int j = lo;
    for (; j + 7 < hi; j += 8) {
        int s0 = idx[j],     s1 = idx[j + 1], s2 = idx[j + 2], s3 = idx[j + 3];
        int s4 = idx[j + 4], s5 = idx[j + 5], s6 = idx[j + 6], s7 = idx[j + 7];
        unsigned int u0 = tab[(size_t)s0 * 8 + lq];
        unsigned int u1 = tab[(size_t)s1 * 8 + lq];
        unsigned int u2 = tab[(size_t)s2 * 8 + lq];
        unsigned int u3 = tab[(size_t)s3 * 8 + lq];
        unsigned int u4 = tab[(size_t)s4 * 8 + lq];
        unsigned int u5 = tab[(size_t)s5 * 8 + lq];
        unsigned int u6 = tab[(size_t)s6 * 8 + lq];
        unsigned int u7 = tab[(size_t)s7 * 8 + lq];
        ACC2(u0) ACC2(u1) ACC2(u2) ACC2(u3) ACC2(u4) ACC2(u5) ACC2(u6) ACC2(u7)
    }
    for (; j + 3 < hi; j += 4) {
        int s0 = idx[j], s1 = idx[j + 1], s2 = idx[j + 2], s3 = idx[j + 3];
        unsigned int u0 = tab[(size_t)s0 * 8 + lq];
        unsigned int u1 = tab[(size_t)s1 * 8 + lq];
        unsigned int u2 = tab[(size_t)s2 * 8 + lq];
        unsigned int u3 = tab[(size_t)s3 * 8 + lq];
        ACC2(u0) ACC2(u1) ACC2(u2) ACC2(u3)
    }
    for (; j < hi; ++j) {
        unsigned int u0 = tab[(size_t)idx[j] * 8 + lq];
        ACC2(u0)
    }
#undef ACC2
}

// Phase B + matvec1: per-bucket counting sort in LDS, coalesced pk write-back,
// then t1 = bf16(deg*x - A@x) in two channel-half passes, indices from LDS.
// BN=128/512thr/24KB LDS -> 4 blocks/CU co-resident (vs 1-2 at BN=256/1024thr),
// grid 782 -> 3.05 blocks/CU (vs 1.53: half the CUs idled in round 2).
__global__ __launch_bounds__(NTB) void phaseB_mv1(int* __restrict__ pk,
                                                  const int* __restrict__ cursor,
                                                  int* __restrict__ row_start,
                                                  int* __restrict__ ideg,
                                                  const unsigned int* __restrict__ xbh,
                                                  unsigned int* __restrict__ t1h, int N) {
    __shared__ int ent[CAPC];
    __shared__ int sorted[CAPC];
    __shared__ int h[BNODE];
    __shared__ int ss[BNODE];
    __shared__ int cur[BNODE];
    int b = blockIdx.x;
    int tid = threadIdx.x;
    int n0 = b << BSH;
    int base = b * CAPC;
    int cnt = min(cursor[b], CAPC);

    if (tid < BNODE) h[tid] = 0;
    __syncthreads();
    for (int i = tid; i < cnt; i += NTB) {
        int en = __builtin_nontemporal_load(&pk[base + i]);
        ent[i] = en;
        atomicAdd(&h[en >> 17], 1);
    }
    __syncthreads();
    int v = 0;
    if (tid < BNODE) { v = h[tid]; ss[tid] = v; }
    __syncthreads();
    for (int off = 1; off < BNODE; off <<= 1) {
        int u = 0;
        if (tid < BNODE && tid >= off) u = ss[tid - off];
        __syncthreads();
        if (tid < BNODE) ss[tid] += u;
        __syncthreads();
    }
    if (tid < BNODE) {
        int exc = ss[tid] - v;
        int n = n0 + tid;
        if (n < N) { row_start[n] = base + exc; ideg[n] = v; }
        cur[tid] = exc;
    }
    __syncthreads();
    for (int i = tid; i < cnt; i += NTB) {
        int en = ent[i];
        int pos = atomicAdd(&cur[en >> 17], 1);
        sorted[pos] = en & SRCMASK;
    }
    __syncthreads();
    for (int i = tid; i < cnt; i += NTB)           // coalesced write-back
        pk[base + i] = sorted[i];

    // ---- matvec1, two channel-half passes ----
    for (int hf = 0; hf < 2; ++hf) {
        const unsigned int* tab = xbh + (size_t)hf * N * 8;
        unsigned int* ttab = t1h + (size_t)hf * N * 8;
        for (int it = tid; it < BNODE * 8; it += NTB) {
            int r = it >> 3;
            int lq = it & 7;
            int n = n0 + r;
            if (n >= N) continue;
            int hi = ss[r];
            int lo = hi - h[r];
            float a0 = 0.f, a1 = 0.f;
            accum_h(tab, sorted, lo, hi, lq, a0, a1);
            unsigned int xs = tab[(size_t)n * 8 + lq];
            float fdg = (float)h[r];
            unsigned int rr = f2bf(fdg * bflo(xs) - a0)
                            | (f2bf(fdg * bfhi(xs) - a1) << 16);
            ttab[(size_t)n * 8 + lq] = rr;   // regular store: stay L2-resident
        }
    }
}

// gather2: stage sorted pk into LDS (coalesced), then
// y = w0*x + w1*t1 + w2*(deg*t1 - A@t1) in two channel-half passes.
__global__ __launch_bounds__(NTB) void gather2_lds(const unsigned int* __restrict__ xbh,
        const unsigned int* __restrict__ t1h, const int* __restrict__ pk,
        const int* __restrict__ cursor, const int* __restrict__ row_start,
        const int* __restrict__ ideg, const float* __restrict__ wts,
        float* __restrict__ y, int N) {
    __shared__ int stg[CAPC];
    int b = blockIdx.x;
    int tid = threadIdx.x;
    int n0 = b << BSH;
    int base = b * CAPC;
    int cnt = min(cursor[b], CAPC);
    for (int i = tid; i < cnt; i += NTB)
        stg[i] = __builtin_nontemporal_load(&pk[base + i]);
    __syncthreads();
    float w0 = wts[0], w1 = wts[1], w2 = wts[2];
    for (int hf = 0; hf < 2; ++hf) {
        const unsigned int* xtab = xbh + (size_t)hf * N * 8;
        const unsigned int* ttab = t1h + (size_t)hf * N * 8;
        for (int it = tid; it < BNODE * 8; it += NTB) {
            int r = it >> 3;
            int lq = it & 7;
            int n = n0 + r;
            if (n >= N) continue;
            int dg = ideg[n];
            int lo = row_start[n] - base;      // local offset in stg
            int hi = lo + dg;
            float a0 = 0.f, a1 = 0.f;
            accum_h(ttab, stg, lo, hi, lq, a0, a1);
            unsigned int xs = xtab[(size_t)n * 8 + lq];
            unsigned int ts = ttab[(size_t)n * 8 + lq];
            float fdg = (float)dg;
            f32x2 yv;
            yv.x = w0 * bflo(xs) + w1 * bflo(ts) + w2 * (fdg * bflo(ts) - a0);
            yv.y = w0 * bfhi(xs) + w1 * bfhi(ts) + w2 * (fdg * bfhi(ts) - a1);
            __builtin_nontemporal_store(yv,
                (f32x2*)(y + (size_t)n * C + hf * 16 + lq * 2));
        }
    }
}

extern "C" void kernel_launch(void* const* d_in, const int* in_sizes, int n_in,
                              void* d_out, int out_size, void* d_ws, size_t ws_size,
                              hipStream_t stream) {
    const float* x    = (const float*)d_in[0];
    const float* wts  = (const float*)d_in[1];
    const int*   esrc = (const int*)d_in[2];
    const int*   edst = (const int*)d_in[3];
    float*       y    = (float*)d_out;

    const int N = in_sizes[0] / C;                 // 100000
    const int E = in_sizes[2];                     // 1600000
    const int nbuck = (N + BNODE - 1) >> BSH;      // 782
    const int nc = N * C;

    char* p = (char*)d_ws;
    auto align16 = [](size_t s) { return (s + 15) & ~(size_t)15; };
    int* cursor    = (int*)p; p += align16((size_t)nbuck * 4);
    int* row_start = (int*)p; p += align16((size_t)N * 4);
    int* ideg      = (int*)p; p += align16((size_t)N * 4);
    int* pk        = (int*)p; p += align16((size_t)nbuck * CAPC * 4);
    unsigned int* xbh = (unsigned int*)p; p += align16((size_t)nc * 2);  // 2 half-tables
    unsigned int* t1h = (unsigned int*)p; p += align16((size_t)nc * 2);
    (void)ws_size;

    (void)hipMemsetAsync(cursor, 0, (size_t)nbuck * 4, stream);

    const int ABLK = 512;
    const int chunk = (E + ABLK - 1) / ABLK;
    const size_t lds_a = (size_t)nbuck * 2 * 4;

    phaseA_cvt<<<ABLK, 1024, lds_a, stream>>>(esrc, edst, cursor, pk, x, xbh,
                                              N, E, nbuck, chunk);
    phaseB_mv1<<<nbuck, NTB, 0, stream>>>(pk, cursor, row_start, ideg,
                                          xbh, t1h, N);
    gather2_lds<<<nbuck, NTB, 0, stream>>>(xbh, t1h, pk, cursor, row_start,
                                           ideg, wts, y, N);
}

// Round 10
// 151.688 us; speedup vs baseline: 1.1269x; 1.0638x over previous
//
#include <hip/hip_runtime.h>

#define C 32
#define BSH 7
#define BNODE 128
#define CAPC 2816          // per-bucket capacity (mean 2048, +17 sigma)
#define NTB 512
#define SRCMASK 0x1FFFF

typedef float f32x4 __attribute__((ext_vector_type(4)));
typedef unsigned int u32x4 __attribute__((ext_vector_type(4)));

__device__ __forceinline__ unsigned int f2bf(float f) {
    unsigned int u = __float_as_uint(f);
    return (u + 0x7FFFu + ((u >> 16) & 1u)) >> 16;   // RNE to bf16
}
__device__ __forceinline__ float bflo(unsigned int u) { return __uint_as_float(u << 16); }
__device__ __forceinline__ float bfhi(unsigned int u) { return __uint_as_float(u & 0xFFFF0000u); }

// Phase A (R6/R9-verified): bucketize by dst>>7 via LDS hist + per-bucket
// global reservation; fused x -> bf16 conversion into ONE 64B-row table
// (uint2 slot q of row n = channels 4q..4q+3).
__global__ __launch_bounds__(1024) void phaseA_cvt(const int* __restrict__ src,
                                                   const int* __restrict__ dst,
                                                   int* __restrict__ cursor,
                                                   int* __restrict__ pk,
                                                   const float* __restrict__ x,
                                                   uint2* __restrict__ xb2,
                                                   int N, int E, int nbuck, int chunk) {
    extern __shared__ int l[];          // lcnt[nbuck] | lcur[nbuck]
    int* lcnt = l;
    int* lcur = l + nbuck;
    int tid = threadIdx.x;
    for (int i = tid; i < nbuck; i += 1024) lcnt[i] = 0;
    __syncthreads();
    int base = blockIdx.x * chunk;
    int end  = min(base + chunk, E);
    for (int e = base + tid; e < end; e += 1024)
        atomicAdd(&lcnt[dst[e] >> BSH], 1);
    __syncthreads();
    for (int i = tid; i < nbuck; i += 1024) {
        int c = lcnt[i];
        lcur[i] = i * CAPC + (c ? atomicAdd(&cursor[i], c) : 0);
    }
    __syncthreads();
    for (int e = base + tid; e < end; e += 1024) {
        int d = dst[e];
        int b = d >> BSH;
        int pos = atomicAdd(&lcur[b], 1);
        pk[pos] = src[e] | ((d & (BNODE - 1)) << 17);
    }
    int total = N * 8;
    int gid = blockIdx.x * 1024 + tid;
    int gth = gridDim.x * 1024;
    for (int i = gid; i < total; i += gth) {
        f32x4 v = *(const f32x4*)(x + (size_t)i * 4);
        uint2 r;
        r.x = f2bf(v.x) | (f2bf(v.y) << 16);
        r.y = f2bf(v.z) | (f2bf(v.w) << 16);
        xb2[i] = r;
    }
}

// accumulate 8 channels (one 16B quarter-row per lane) over LDS indices
// idx[lo..hi). 8-deep unroll: 8 independent 16B gathers in flight per lane;
// 4 lanes cover a full 64B row -> 16 entries per wave load instruction
// (4x fewer gather instructions + 4x fewer serial walks/thread than the
// 4B-per-lane scheme of R6-R9).
__device__ __forceinline__ void accum_q(const u32x4* __restrict__ tab,
                                        const int* idx, int lo, int hi, int lqq,
                                        float& a0, float& a1, float& a2, float& a3,
                                        float& a4, float& a5, float& a6, float& a7) {
#define ACC8(u) { a0 += bflo(u.x); a1 += bfhi(u.x); a2 += bflo(u.y); a3 += bfhi(u.y); \
                  a4 += bflo(u.z); a5 += bfhi(u.z); a6 += bflo(u.w); a7 += bfhi(u.w); }
    int j = lo;
    for (; j + 7 < hi; j += 8) {
        int s0 = idx[j],     s1 = idx[j + 1], s2 = idx[j + 2], s3 = idx[j + 3];
        int s4 = idx[j + 4], s5 = idx[j + 5], s6 = idx[j + 6], s7 = idx[j + 7];
        u32x4 u0 = tab[(size_t)s0 * 4 + lqq];
        u32x4 u1 = tab[(size_t)s1 * 4 + lqq];
        u32x4 u2 = tab[(size_t)s2 * 4 + lqq];
        u32x4 u3 = tab[(size_t)s3 * 4 + lqq];
        u32x4 u4 = tab[(size_t)s4 * 4 + lqq];
        u32x4 u5 = tab[(size_t)s5 * 4 + lqq];
        u32x4 u6 = tab[(size_t)s6 * 4 + lqq];
        u32x4 u7 = tab[(size_t)s7 * 4 + lqq];
        ACC8(u0) ACC8(u1) ACC8(u2) ACC8(u3) ACC8(u4) ACC8(u5) ACC8(u6) ACC8(u7)
    }
    for (; j + 3 < hi; j += 4) {
        int s0 = idx[j], s1 = idx[j + 1], s2 = idx[j + 2], s3 = idx[j + 3];
        u32x4 u0 = tab[(size_t)s0 * 4 + lqq];
        u32x4 u1 = tab[(size_t)s1 * 4 + lqq];
        u32x4 u2 = tab[(size_t)s2 * 4 + lqq];
        u32x4 u3 = tab[(size_t)s3 * 4 + lqq];
        ACC8(u0) ACC8(u1) ACC8(u2) ACC8(u3)
    }
    for (; j < hi; ++j) {
        u32x4 u0 = tab[(size_t)idx[j] * 4 + lqq];
        ACC8(u0)
    }
#undef ACC8
}

// Phase B + matvec1: per-bucket counting sort in LDS (verified), coalesced pk
// write-back, then t1 = bf16(deg*x - A@x). One walk per thread:
// thread = (node r = it>>2, quarter-row lqq = it&3), 128 nodes x 4 lanes = 512.
__global__ __launch_bounds__(NTB) void phaseB_mv1(int* __restrict__ pk,
                                                  const int* __restrict__ cursor,
                                                  int* __restrict__ row_start,
                                                  int* __restrict__ ideg,
                                                  const u32x4* __restrict__ xb4,
                                                  u32x4* __restrict__ t14, int N) {
    __shared__ int ent[CAPC];
    __shared__ int sorted[CAPC];
    __shared__ int h[BNODE];
    __shared__ int ss[BNODE];
    __shared__ int cur[BNODE];
    int b = blockIdx.x;
    int tid = threadIdx.x;
    int n0 = b << BSH;
    int base = b * CAPC;
    int cnt = min(cursor[b], CAPC);

    if (tid < BNODE) h[tid] = 0;
    __syncthreads();
    for (int i = tid; i < cnt; i += NTB) {
        int en = __builtin_nontemporal_load(&pk[base + i]);
        ent[i] = en;
        atomicAdd(&h[en >> 17], 1);
    }
    __syncthreads();
    int v = 0;
    if (tid < BNODE) { v = h[tid]; ss[tid] = v; }
    __syncthreads();
    for (int off = 1; off < BNODE; off <<= 1) {
        int u = 0;
        if (tid < BNODE && tid >= off) u = ss[tid - off];
        __syncthreads();
        if (tid < BNODE) ss[tid] += u;
        __syncthreads();
    }
    if (tid < BNODE) {
        int exc = ss[tid] - v;
        int n = n0 + tid;
        if (n < N) { row_start[n] = base + exc; ideg[n] = v; }
        cur[tid] = exc;
    }
    __syncthreads();
    for (int i = tid; i < cnt; i += NTB) {
        int en = ent[i];
        int pos = atomicAdd(&cur[en >> 17], 1);
        sorted[pos] = en & SRCMASK;
    }
    __syncthreads();
    for (int i = tid; i < cnt; i += NTB)           // coalesced write-back
        pk[base + i] = sorted[i];

    // ---- matvec1: one walk per thread ----
    for (int it = tid; it < BNODE * 4; it += NTB) {
        int r = it >> 2;
        int lqq = it & 3;
        int n = n0 + r;
        if (n >= N) continue;
        int hi = ss[r];
        int lo = hi - h[r];
        float a0 = 0.f, a1 = 0.f, a2 = 0.f, a3 = 0.f;
        float a4 = 0.f, a5 = 0.f, a6 = 0.f, a7 = 0.f;
        accum_q(xb4, sorted, lo, hi, lqq, a0, a1, a2, a3, a4, a5, a6, a7);
        u32x4 xs = xb4[(size_t)n * 4 + lqq];
        float fdg = (float)h[r];
        u32x4 rr;
        rr.x = f2bf(fdg * bflo(xs.x) - a0) | (f2bf(fdg * bfhi(xs.x) - a1) << 16);
        rr.y = f2bf(fdg * bflo(xs.y) - a2) | (f2bf(fdg * bfhi(xs.y) - a3) << 16);
        rr.z = f2bf(fdg * bflo(xs.z) - a4) | (f2bf(fdg * bfhi(xs.z) - a5) << 16);
        rr.w = f2bf(fdg * bflo(xs.w) - a6) | (f2bf(fdg * bfhi(xs.w) - a7) << 16);
        t14[(size_t)n * 4 + lqq] = rr;   // regular store: stay cache-resident
    }
}

// gather2: stage sorted pk into LDS (coalesced), then
// y = w0*x + w1*t1 + w2*(deg*t1 - A@t1), one walk per thread.
__global__ __launch_bounds__(NTB) void gather2_lds(const u32x4* __restrict__ xb4,
        const u32x4* __restrict__ t14, const int* __restrict__ pk,
        const int* __restrict__ cursor, const int* __restrict__ row_start,
        const int* __restrict__ ideg, const float* __restrict__ wts,
        float* __restrict__ y, int N) {
    __shared__ int stg[CAPC];
    int b = blockIdx.x;
    int tid = threadIdx.x;
    int n0 = b << BSH;
    int base = b * CAPC;
    int cnt = min(cursor[b], CAPC);
    for (int i = tid; i < cnt; i += NTB)
        stg[i] = __builtin_nontemporal_load(&pk[base + i]);
    __syncthreads();
    float w0 = wts[0], w1 = wts[1], w2 = wts[2];
    for (int it = tid; it < BNODE * 4; it += NTB) {
        int r = it >> 2;
        int lqq = it & 3;
        int n = n0 + r;
        if (n >= N) continue;
        int dg = ideg[n];
        int lo = row_start[n] - base;          // local offset in stg
        int hi = lo + dg;
        float a0 = 0.f, a1 = 0.f, a2 = 0.f, a3 = 0.f;
        float a4 = 0.f, a5 = 0.f, a6 = 0.f, a7 = 0.f;
        accum_q(t14, stg, lo, hi, lqq, a0, a1, a2, a3, a4, a5, a6, a7);
        u32x4 xs = xb4[(size_t)n * 4 + lqq];
        u32x4 ts = t14[(size_t)n * 4 + lqq];
        float fdg = (float)dg;
        f32x4 y0, y1;
        y0.x = w0 * bflo(xs.x) + w1 * bflo(ts.x) + w2 * (fdg * bflo(ts.x) - a0);
        y0.y = w0 * bfhi(xs.x) + w1 * bfhi(ts.x) + w2 * (fdg * bfhi(ts.x) - a1);
        y0.z = w0 * bflo(xs.y) + w1 * bflo(ts.y) + w2 * (fdg * bflo(ts.y) - a2);
        y0.w = w0 * bfhi(xs.y) + w1 * bfhi(ts.y) + w2 * (fdg * bfhi(ts.y) - a3);
        y1.x = w0 * bflo(xs.z) + w1 * bflo(ts.z) + w2 * (fdg * bflo(ts.z) - a4);
        y1.y = w0 * bfhi(xs.z) + w1 * bfhi(ts.z) + w2 * (fdg * bfhi(ts.z) - a5);
        y1.z = w0 * bflo(xs.w) + w1 * bflo(ts.w) + w2 * (fdg * bflo(ts.w) - a6);
        y1.w = w0 * bfhi(xs.w) + w1 * bfhi(ts.w) + w2 * (fdg * bfhi(ts.w) - a7);
        float* yo = y + (size_t)n * C + lqq * 8;   // channels 8*lqq .. 8*lqq+7
        __builtin_nontemporal_store(y0, (f32x4*)yo);
        __builtin_nontemporal_store(y1, (f32x4*)(yo + 4));
    }
}

extern "C" void kernel_launch(void* const* d_in, const int* in_sizes, int n_in,
                              void* d_out, int out_size, void* d_ws, size_t ws_size,
                              hipStream_t stream) {
    const float* x    = (const float*)d_in[0];
    const float* wts  = (const float*)d_in[1];
    const int*   esrc = (const int*)d_in[2];
    const int*   edst = (const int*)d_in[3];
    float*       y    = (float*)d_out;

    const int N = in_sizes[0] / C;                 // 100000
    const int E = in_sizes[2];                     // 1600000
    const int nbuck = (N + BNODE - 1) >> BSH;      // 782
    const int nc = N * C;

    char* p = (char*)d_ws;
    auto align16 = [](size_t s) { return (s + 15) & ~(size_t)15; };
    int* cursor    = (int*)p; p += align16((size_t)nbuck * 4);
    int* row_start = (int*)p; p += align16((size_t)N * 4);
    int* ideg      = (int*)p; p += align16((size_t)N * 4);
    int* pk        = (int*)p; p += align16((size_t)nbuck * CAPC * 4);
    u32x4* xb4     = (u32x4*)p; p += align16((size_t)nc * 2);   // 64B rows
    u32x4* t14     = (u32x4*)p; p += align16((size_t)nc * 2);
    (void)ws_size;

    (void)hipMemsetAsync(cursor, 0, (size_t)nbuck * 4, stream);

    const int ABLK = 512;
    const int chunk = (E + ABLK - 1) / ABLK;
    const size_t lds_a = (size_t)nbuck * 2 * 4;

    phaseA_cvt<<<ABLK, 1024, lds_a, stream>>>(esrc, edst, cursor, pk, x,
                                              (uint2*)xb4, N, E, nbuck, chunk);
    phaseB_mv1<<<nbuck, NTB, 0, stream>>>(pk, cursor, row_start, ideg,
                                          xb4, t14, N);
    gather2_lds<<<nbuck, NTB, 0, stream>>>(xb4, t14, pk, cursor, row_start,
                                           ideg, wts, y, N);
}

// Round 11
// 148.264 us; speedup vs baseline: 1.1529x; 1.0231x over previous
//
#include <hip/hip_runtime.h>

#define C 32
#define BSH 7
#define BNODE 128
#define CAPC 2816          // per-bucket capacity (mean 2048, +17 sigma)
#define NTB 512
#define SRCMASK 0x1FFFF

typedef float f32x4 __attribute__((ext_vector_type(4)));
typedef unsigned int u32x4 __attribute__((ext_vector_type(4)));

__device__ __forceinline__ unsigned int f2bf(float f) {
    unsigned int u = __float_as_uint(f);
    return (u + 0x7FFFu + ((u >> 16) & 1u)) >> 16;   // RNE to bf16
}
__device__ __forceinline__ float bflo(unsigned int u) { return __uint_as_float(u << 16); }
__device__ __forceinline__ float bfhi(unsigned int u) { return __uint_as_float(u & 0xFFFF0000u); }

// Phase A (R10-verified): bucketize by dst>>7 via LDS hist + per-bucket
// global reservation; fused x -> bf16 conversion into ONE 64B-row table.
__global__ __launch_bounds__(1024) void phaseA_cvt(const int* __restrict__ src,
                                                   const int* __restrict__ dst,
                                                   int* __restrict__ cursor,
                                                   int* __restrict__ pk,
                                                   const float* __restrict__ x,
                                                   uint2* __restrict__ xb2,
                                                   int N, int E, int nbuck, int chunk) {
    extern __shared__ int l[];          // lcnt[nbuck] | lcur[nbuck]
    int* lcnt = l;
    int* lcur = l + nbuck;
    int tid = threadIdx.x;
    for (int i = tid; i < nbuck; i += 1024) lcnt[i] = 0;
    __syncthreads();
    int base = blockIdx.x * chunk;
    int end  = min(base + chunk, E);
    for (int e = base + tid; e < end; e += 1024)
        atomicAdd(&lcnt[dst[e] >> BSH], 1);
    __syncthreads();
    for (int i = tid; i < nbuck; i += 1024) {
        int c = lcnt[i];
        lcur[i] = i * CAPC + (c ? atomicAdd(&cursor[i], c) : 0);
    }
    __syncthreads();
    for (int e = base + tid; e < end; e += 1024) {
        int d = dst[e];
        int b = d >> BSH;
        int pos = atomicAdd(&lcur[b], 1);
        pk[pos] = src[e] | ((d & (BNODE - 1)) << 17);
    }
    int total = N * 8;
    int gid = blockIdx.x * 1024 + tid;
    int gth = gridDim.x * 1024;
    for (int i = gid; i < total; i += gth) {
        f32x4 v = *(const f32x4*)(x + (size_t)i * 4);
        uint2 r;
        r.x = f2bf(v.x) | (f2bf(v.y) << 16);
        r.y = f2bf(v.z) | (f2bf(v.w) << 16);
        xb2[i] = r;
    }
}

// accumulate 8 channels (one 16B quarter-row per lane) over LDS indices
// idx[lo..hi). 4-deep unroll (16 load-VGPRs) so the walk kernels fit in
// 64 VGPR -> 8 waves/SIMD (R9 lesson: blocks/CU without a VGPR-band change
// leaves waves/CU fixed; this is the occupancy lever actually untried).
__device__ __forceinline__ void accum_q(const u32x4* __restrict__ tab,
                                        const int* idx, int lo, int hi, int lqq,
                                        float& a0, float& a1, float& a2, float& a3,
                                        float& a4, float& a5, float& a6, float& a7) {
#define ACC8(u) { a0 += bflo(u.x); a1 += bfhi(u.x); a2 += bflo(u.y); a3 += bfhi(u.y); \
                  a4 += bflo(u.z); a5 += bfhi(u.z); a6 += bflo(u.w); a7 += bfhi(u.w); }
    int j = lo;
    for (; j + 3 < hi; j += 4) {
        int s0 = idx[j], s1 = idx[j + 1], s2 = idx[j + 2], s3 = idx[j + 3];
        u32x4 u0 = tab[(size_t)s0 * 4 + lqq];
        u32x4 u1 = tab[(size_t)s1 * 4 + lqq];
        u32x4 u2 = tab[(size_t)s2 * 4 + lqq];
        u32x4 u3 = tab[(size_t)s3 * 4 + lqq];
        ACC8(u0) ACC8(u1) ACC8(u2) ACC8(u3)
    }
    for (; j < hi; ++j) {
        u32x4 u0 = tab[(size_t)idx[j] * 4 + lqq];
        ACC8(u0)
    }
#undef ACC8
}

// Phase B + matvec1: per-bucket counting sort in LDS (verified), coalesced pk
// write-back, then t1 = bf16(deg*x - A@x). One walk per thread:
// (node r = it>>2, quarter-row lqq = it&3); 128 nodes x 4 lanes = 512 threads.
__global__ __launch_bounds__(NTB, 8) void phaseB_mv1(int* __restrict__ pk,
                                                     const int* __restrict__ cursor,
                                                     int* __restrict__ row_start,
                                                     int* __restrict__ ideg,
                                                     const u32x4* __restrict__ xb4,
                                                     u32x4* __restrict__ t14, int N) {
    __shared__ int ent[CAPC];
    __shared__ int sorted[CAPC];
    __shared__ int h[BNODE];
    __shared__ int ss[BNODE];
    __shared__ int cur[BNODE];
    int b = blockIdx.x;
    int tid = threadIdx.x;
    int n0 = b << BSH;
    int base = b * CAPC;
    int cnt = min(cursor[b], CAPC);

    if (tid < BNODE) h[tid] = 0;
    __syncthreads();
    for (int i = tid; i < cnt; i += NTB) {
        int en = __builtin_nontemporal_load(&pk[base + i]);
        ent[i] = en;
        atomicAdd(&h[en >> 17], 1);
    }
    __syncthreads();
    int v = 0;
    if (tid < BNODE) { v = h[tid]; ss[tid] = v; }
    __syncthreads();
    for (int off = 1; off < BNODE; off <<= 1) {
        int u = 0;
        if (tid < BNODE && tid >= off) u = ss[tid - off];
        __syncthreads();
        if (tid < BNODE) ss[tid] += u;
        __syncthreads();
    }
    if (tid < BNODE) {
        int exc = ss[tid] - v;
        int n = n0 + tid;
        if (n < N) { row_start[n] = base + exc; ideg[n] = v; }
        cur[tid] = exc;
    }
    __syncthreads();
    for (int i = tid; i < cnt; i += NTB) {
        int en = ent[i];
        int pos = atomicAdd(&cur[en >> 17], 1);
        sorted[pos] = en & SRCMASK;
    }
    __syncthreads();
    for (int i = tid; i < cnt; i += NTB)           // coalesced write-back
        pk[base + i] = sorted[i];

    // ---- matvec1: one walk per thread ----
    for (int it = tid; it < BNODE * 4; it += NTB) {
        int r = it >> 2;
        int lqq = it & 3;
        int n = n0 + r;
        if (n >= N) continue;
        int hi = ss[r];
        int lo = hi - h[r];
        float a0 = 0.f, a1 = 0.f, a2 = 0.f, a3 = 0.f;
        float a4 = 0.f, a5 = 0.f, a6 = 0.f, a7 = 0.f;
        accum_q(xb4, sorted, lo, hi, lqq, a0, a1, a2, a3, a4, a5, a6, a7);
        u32x4 xs = xb4[(size_t)n * 4 + lqq];
        float fdg = (float)h[r];
        u32x4 rr;
        rr.x = f2bf(fdg * bflo(xs.x) - a0) | (f2bf(fdg * bfhi(xs.x) - a1) << 16);
        rr.y = f2bf(fdg * bflo(xs.y) - a2) | (f2bf(fdg * bfhi(xs.y) - a3) << 16);
        rr.z = f2bf(fdg * bflo(xs.z) - a4) | (f2bf(fdg * bfhi(xs.z) - a5) << 16);
        rr.w = f2bf(fdg * bflo(xs.w) - a6) | (f2bf(fdg * bfhi(xs.w) - a7) << 16);
        t14[(size_t)n * 4 + lqq] = rr;   // regular store: stay cache-resident
    }
}

// gather2: stage sorted pk into LDS (coalesced), then
// y = w0*x + w1*t1 + w2*(deg*t1 - A@t1), one walk per thread.
__global__ __launch_bounds__(NTB, 8) void gather2_lds(const u32x4* __restrict__ xb4,
        const u32x4* __restrict__ t14, const int* __restrict__ pk,
        const int* __restrict__ cursor, const int* __restrict__ row_start,
        const int* __restrict__ ideg, const float* __restrict__ wts,
        float* __restrict__ y, int N) {
    __shared__ int stg[CAPC];
    int b = blockIdx.x;
    int tid = threadIdx.x;
    int n0 = b << BSH;
    int base = b * CAPC;
    int cnt = min(cursor[b], CAPC);
    for (int i = tid; i < cnt; i += NTB)
        stg[i] = __builtin_nontemporal_load(&pk[base + i]);
    __syncthreads();
    float w0 = wts[0], w1 = wts[1], w2 = wts[2];
    for (int it = tid; it < BNODE * 4; it += NTB) {
        int r = it >> 2;
        int lqq = it & 3;
        int n = n0 + r;
        if (n >= N) continue;
        int dg = ideg[n];
        int lo = row_start[n] - base;          // local offset in stg
        int hi = lo + dg;
        float a0 = 0.f, a1 = 0.f, a2 = 0.f, a3 = 0.f;
        float a4 = 0.f, a5 = 0.f, a6 = 0.f, a7 = 0.f;
        accum_q(t14, stg, lo, hi, lqq, a0, a1, a2, a3, a4, a5, a6, a7);
        u32x4 xs = xb4[(size_t)n * 4 + lqq];
        u32x4 ts = t14[(size_t)n * 4 + lqq];
        float fdg = (float)dg;
        f32x4 y0, y1;
        y0.x = w0 * bflo(xs.x) + w1 * bflo(ts.x) + w2 * (fdg * bflo(ts.x) - a0);
        y0.y = w0 * bfhi(xs.x) + w1 * bfhi(ts.x) + w2 * (fdg * bfhi(ts.x) - a1);
        y0.z = w0 * bflo(xs.y) + w1 * bflo(ts.y) + w2 * (fdg * bflo(ts.y) - a2);
        y0.w = w0 * bfhi(xs.y) + w1 * bfhi(ts.y) + w2 * (fdg * bfhi(ts.y) - a3);
        y1.x = w0 * bflo(xs.z) + w1 * bflo(ts.z) + w2 * (fdg * bflo(ts.z) - a4);
        y1.y = w0 * bfhi(xs.z) + w1 * bfhi(ts.z) + w2 * (fdg * bfhi(ts.z) - a5);
        y1.z = w0 * bflo(xs.w) + w1 * bflo(ts.w) + w2 * (fdg * bflo(ts.w) - a6);
        y1.w = w0 * bfhi(xs.w) + w1 * bfhi(ts.w) + w2 * (fdg * bfhi(ts.w) - a7);
        float* yo = y + (size_t)n * C + lqq * 8;   // channels 8*lqq .. 8*lqq+7
        __builtin_nontemporal_store(y0, (f32x4*)yo);
        __builtin_nontemporal_store(y1, (f32x4*)(yo + 4));
    }
}

extern "C" void kernel_launch(void* const* d_in, const int* in_sizes, int n_in,
                              void* d_out, int out_size, void* d_ws, size_t ws_size,
                              hipStream_t stream) {
    const float* x    = (const float*)d_in[0];
    const float* wts  = (const float*)d_in[1];
    const int*   esrc = (const int*)d_in[2];
    const int*   edst = (const int*)d_in[3];
    float*       y    = (float*)d_out;

    const int N = in_sizes[0] / C;                 // 100000
    const int E = in_sizes[2];                     // 1600000
    const int nbuck = (N + BNODE - 1) >> BSH;      // 782
    const int nc = N * C;

    char* p = (char*)d_ws;
    auto align16 = [](size_t s) { return (s + 15) & ~(size_t)15; };
    int* cursor    = (int*)p; p += align16((size_t)nbuck * 4);
    int* row_start = (int*)p; p += align16((size_t)N * 4);
    int* ideg      = (int*)p; p += align16((size_t)N * 4);
    int* pk        = (int*)p; p += align16((size_t)nbuck * CAPC * 4);
    u32x4* xb4     = (u32x4*)p; p += align16((size_t)nc * 2);   // 64B rows
    u32x4* t14     = (u32x4*)p; p += align16((size_t)nc * 2);
    (void)ws_size;

    (void)hipMemsetAsync(cursor, 0, (size_t)nbuck * 4, stream);

    const int ABLK = 512;
    const int chunk = (E + ABLK - 1) / ABLK;
    const size_t lds_a = (size_t)nbuck * 2 * 4;

    phaseA_cvt<<<ABLK, 1024, lds_a, stream>>>(esrc, edst, cursor, pk, x,
                                              (uint2*)xb4, N, E, nbuck, chunk);
    phaseB_mv1<<<nbuck, NTB, 0, stream>>>(pk, cursor, row_start, ideg,
                                          xb4, t14, N);
    gather2_lds<<<nbuck, NTB, 0, stream>>>(xb4, t14, pk, cursor, row_start,
                                           ideg, wts, y, N);
}

// Round 12
// 142.403 us; speedup vs baseline: 1.2003x; 1.0412x over previous
//
#include <hip/hip_runtime.h>

#define C 32
#define BSH 7
#define BNODE 128
#define CAPC 2816          // per-bucket capacity (mean 2048, +17 sigma)
#define NTB 512
#define SRCMASK 0x1FFFF

typedef float f32x4 __attribute__((ext_vector_type(4)));
typedef unsigned int u32x4 __attribute__((ext_vector_type(4)));

__device__ __forceinline__ unsigned int f2bf(float f) {
    unsigned int u = __float_as_uint(f);
    return (u + 0x7FFFu + ((u >> 16) & 1u)) >> 16;   // RNE to bf16
}
__device__ __forceinline__ float bflo(unsigned int u) { return __uint_as_float(u << 16); }
__device__ __forceinline__ float bfhi(unsigned int u) { return __uint_as_float(u & 0xFFFF0000u); }

// Phase A: bucketize by dst>>7 via LDS hist + per-bucket global reservation;
// fused x -> bf16 conversion into ONE 64B-row table. ABLK=256 (was 512):
// chunk doubles -> ~8-word (32B) pk runs per (block,bucket), halving the
// partial-line write amp that R8's bucket-halving silently introduced.
__global__ __launch_bounds__(1024) void phaseA_cvt(const int* __restrict__ src,
                                                   const int* __restrict__ dst,
                                                   int* __restrict__ cursor,
                                                   int* __restrict__ pk,
                                                   const float* __restrict__ x,
                                                   uint2* __restrict__ xb2,
                                                   int N, int E, int nbuck, int chunk) {
    extern __shared__ int l[];          // lcnt[nbuck] | lcur[nbuck]
    int* lcnt = l;
    int* lcur = l + nbuck;
    int tid = threadIdx.x;
    for (int i = tid; i < nbuck; i += 1024) lcnt[i] = 0;
    __syncthreads();
    int base = blockIdx.x * chunk;
    int end  = min(base + chunk, E);
    for (int e = base + tid; e < end; e += 1024)
        atomicAdd(&lcnt[dst[e] >> BSH], 1);
    __syncthreads();
    for (int i = tid; i < nbuck; i += 1024) {
        int c = lcnt[i];
        lcur[i] = i * CAPC + (c ? atomicAdd(&cursor[i], c) : 0);
    }
    __syncthreads();
    for (int e = base + tid; e < end; e += 1024) {
        int d = dst[e];
        int b = d >> BSH;
        int pos = atomicAdd(&lcur[b], 1);
        pk[pos] = src[e] | ((d & (BNODE - 1)) << 17);
    }
    int total = N * 8;
    int gid = blockIdx.x * 1024 + tid;
    int gth = gridDim.x * 1024;
    for (int i = gid; i < total; i += gth) {
        f32x4 v = *(const f32x4*)(x + (size_t)i * 4);
        uint2 r;
        r.x = f2bf(v.x) | (f2bf(v.y) << 16);
        r.y = f2bf(v.z) | (f2bf(v.w) << 16);
        xb2[i] = r;
    }
}

// accumulate 8 channels (one 16B quarter-row per lane) over LDS indices
// idx[lo..hi). 4-deep unroll: fits 64-VGPR band -> 8 waves/SIMD (R11-verified).
__device__ __forceinline__ void accum_q(const u32x4* __restrict__ tab,
                                        const int* idx, int lo, int hi, int lqq,
                                        float& a0, float& a1, float& a2, float& a3,
                                        float& a4, float& a5, float& a6, float& a7) {
#define ACC8(u) { a0 += bflo(u.x); a1 += bfhi(u.x); a2 += bflo(u.y); a3 += bfhi(u.y); \
                  a4 += bflo(u.z); a5 += bfhi(u.z); a6 += bflo(u.w); a7 += bfhi(u.w); }
    int j = lo;
    for (; j + 3 < hi; j += 4) {
        int s0 = idx[j], s1 = idx[j + 1], s2 = idx[j + 2], s3 = idx[j + 3];
        u32x4 u0 = tab[(size_t)s0 * 4 + lqq];
        u32x4 u1 = tab[(size_t)s1 * 4 + lqq];
        u32x4 u2 = tab[(size_t)s2 * 4 + lqq];
        u32x4 u3 = tab[(size_t)s3 * 4 + lqq];
        ACC8(u0) ACC8(u1) ACC8(u2) ACC8(u3)
    }
    for (; j < hi; ++j) {
        u32x4 u0 = tab[(size_t)idx[j] * 4 + lqq];
        ACC8(u0)
    }
#undef ACC8
}

// Phase B + matvec1: per-bucket counting sort in LDS, coalesced pk write-back,
// then t1 = bf16(deg*x - A@x). Self-row load (xs) hoisted to kernel entry so
// its latency hides under the whole sort phase.
__global__ __launch_bounds__(NTB, 8) void phaseB_mv1(int* __restrict__ pk,
                                                     const int* __restrict__ cursor,
                                                     int* __restrict__ row_start,
                                                     int* __restrict__ ideg,
                                                     const u32x4* __restrict__ xb4,
                                                     u32x4* __restrict__ t14, int N) {
    __shared__ int ent[CAPC];
    __shared__ int sorted[CAPC];
    __shared__ int h[BNODE];
    __shared__ int ss[BNODE];
    __shared__ int cur[BNODE];
    int b = blockIdx.x;
    int tid = threadIdx.x;
    int n0 = b << BSH;
    int base = b * CAPC;
    int cnt = min(cursor[b], CAPC);

    // hoisted self-row load (independent of sort)
    int rw = tid >> 2;
    int lqq = tid & 3;
    int nw = n0 + rw;
    u32x4 xs = {0u, 0u, 0u, 0u};
    if (nw < N) xs = xb4[(size_t)nw * 4 + lqq];

    if (tid < BNODE) h[tid] = 0;
    __syncthreads();
    for (int i = tid; i < cnt; i += NTB) {
        int en = __builtin_nontemporal_load(&pk[base + i]);
        ent[i] = en;
        atomicAdd(&h[en >> 17], 1);
    }
    __syncthreads();
    int v = 0;
    if (tid < BNODE) { v = h[tid]; ss[tid] = v; }
    __syncthreads();
    for (int off = 1; off < BNODE; off <<= 1) {
        int u = 0;
        if (tid < BNODE && tid >= off) u = ss[tid - off];
        __syncthreads();
        if (tid < BNODE) ss[tid] += u;
        __syncthreads();
    }
    if (tid < BNODE) {
        int exc = ss[tid] - v;
        int n = n0 + tid;
        if (n < N) { row_start[n] = base + exc; ideg[n] = v; }
        cur[tid] = exc;
    }
    __syncthreads();
    for (int i = tid; i < cnt; i += NTB) {
        int en = ent[i];
        int pos = atomicAdd(&cur[en >> 17], 1);
        sorted[pos] = en & SRCMASK;
    }
    __syncthreads();
    for (int i = tid; i < cnt; i += NTB)           // coalesced write-back
        pk[base + i] = sorted[i];

    // ---- matvec1: one walk per thread ----
    if (nw < N) {
        int hi = ss[rw];
        int lo = hi - h[rw];
        float a0 = 0.f, a1 = 0.f, a2 = 0.f, a3 = 0.f;
        float a4 = 0.f, a5 = 0.f, a6 = 0.f, a7 = 0.f;
        accum_q(xb4, sorted, lo, hi, lqq, a0, a1, a2, a3, a4, a5, a6, a7);
        float fdg = (float)h[rw];
        u32x4 rr;
        rr.x = f2bf(fdg * bflo(xs.x) - a0) | (f2bf(fdg * bfhi(xs.x) - a1) << 16);
        rr.y = f2bf(fdg * bflo(xs.y) - a2) | (f2bf(fdg * bfhi(xs.y) - a3) << 16);
        rr.z = f2bf(fdg * bflo(xs.z) - a4) | (f2bf(fdg * bfhi(xs.z) - a5) << 16);
        rr.w = f2bf(fdg * bflo(xs.w) - a6) | (f2bf(fdg * bfhi(xs.w) - a7) << 16);
        t14[(size_t)nw * 4 + lqq] = rr;  // regular store: stay cache-resident
    }
}

// gather2: self-row loads (xs/ts/bounds) issued at entry, staging of sorted pk
// into LDS overlaps them, then y = w0*x + w1*t1 + w2*(deg*t1 - A@t1).
__global__ __launch_bounds__(NTB, 8) void gather2_lds(const u32x4* __restrict__ xb4,
        const u32x4* __restrict__ t14, const int* __restrict__ pk,
        const int* __restrict__ cursor, const int* __restrict__ row_start,
        const int* __restrict__ ideg, const float* __restrict__ wts,
        float* __restrict__ y, int N) {
    __shared__ int stg[CAPC];
    int b = blockIdx.x;
    int tid = threadIdx.x;
    int n0 = b << BSH;
    int base = b * CAPC;
    int cnt = min(cursor[b], CAPC);

    // hoisted per-thread loads (independent of staging)
    int rw = tid >> 2;
    int lqq = tid & 3;
    int nw = n0 + rw;
    u32x4 xs = {0u, 0u, 0u, 0u}, ts = {0u, 0u, 0u, 0u};
    int dg = 0, lo = 0;
    if (nw < N) {
        xs = xb4[(size_t)nw * 4 + lqq];
        ts = t14[(size_t)nw * 4 + lqq];
        dg = ideg[nw];
        lo = row_start[nw] - base;
    }
    float w0 = wts[0], w1 = wts[1], w2 = wts[2];

    for (int i = tid; i < cnt; i += NTB)
        stg[i] = __builtin_nontemporal_load(&pk[base + i]);
    __syncthreads();

    if (nw < N) {
        int hi = lo + dg;
        float a0 = 0.f, a1 = 0.f, a2 = 0.f, a3 = 0.f;
        float a4 = 0.f, a5 = 0.f, a6 = 0.f, a7 = 0.f;
        accum_q(t14, stg, lo, hi, lqq, a0, a1, a2, a3, a4, a5, a6, a7);
        float fdg = (float)dg;
        f32x4 y0, y1;
        y0.x = w0 * bflo(xs.x) + w1 * bflo(ts.x) + w2 * (fdg * bflo(ts.x) - a0);
        y0.y = w0 * bfhi(xs.x) + w1 * bfhi(ts.x) + w2 * (fdg * bfhi(ts.x) - a1);
        y0.z = w0 * bflo(xs.y) + w1 * bflo(ts.y) + w2 * (fdg * bflo(ts.y) - a2);
        y0.w = w0 * bfhi(xs.y) + w1 * bfhi(ts.y) + w2 * (fdg * bfhi(ts.y) - a3);
        y1.x = w0 * bflo(xs.z) + w1 * bflo(ts.z) + w2 * (fdg * bflo(ts.z) - a4);
        y1.y = w0 * bfhi(xs.z) + w1 * bfhi(ts.z) + w2 * (fdg * bfhi(ts.z) - a5);
        y1.z = w0 * bflo(xs.w) + w1 * bflo(ts.w) + w2 * (fdg * bflo(ts.w) - a6);
        y1.w = w0 * bfhi(xs.w) + w1 * bfhi(ts.w) + w2 * (fdg * bfhi(ts.w) - a7);
        float* yo = y + (size_t)nw * C + lqq * 8;  // channels 8*lqq .. 8*lqq+7
        __builtin_nontemporal_store(y0, (f32x4*)yo);
        __builtin_nontemporal_store(y1, (f32x4*)(yo + 4));
    }
}

extern "C" void kernel_launch(void* const* d_in, const int* in_sizes, int n_in,
                              void* d_out, int out_size, void* d_ws, size_t ws_size,
                              hipStream_t stream) {
    const float* x    = (const float*)d_in[0];
    const float* wts  = (const float*)d_in[1];
    const int*   esrc = (const int*)d_in[2];
    const int*   edst = (const int*)d_in[3];
    float*       y    = (float*)d_out;

    const int N = in_sizes[0] / C;                 // 100000
    const int E = in_sizes[2];                     // 1600000
    const int nbuck = (N + BNODE - 1) >> BSH;      // 782
    const int nc = N * C;

    char* p = (char*)d_ws;
    auto align16 = [](size_t s) { return (s + 15) & ~(size_t)15; };
    int* cursor    = (int*)p; p += align16((size_t)nbuck * 4);
    int* row_start = (int*)p; p += align16((size_t)N * 4);
    int* ideg      = (int*)p; p += align16((size_t)N * 4);
    int* pk        = (int*)p; p += align16((size_t)nbuck * CAPC * 4);
    u32x4* xb4     = (u32x4*)p; p += align16((size_t)nc * 2);   // 64B rows
    u32x4* t14     = (u32x4*)p; p += align16((size_t)nc * 2);
    (void)ws_size;

    (void)hipMemsetAsync(cursor, 0, (size_t)nbuck * 4, stream);

    const int ABLK = 256;                          // 8-word pk runs per bucket
    const int chunk = (E + ABLK - 1) / ABLK;
    const size_t lds_a = (size_t)nbuck * 2 * 4;

    phaseA_cvt<<<ABLK, 1024, lds_a, stream>>>(esrc, edst, cursor, pk, x,
                                              (uint2*)xb4, N, E, nbuck, chunk);
    phaseB_mv1<<<nbuck, NTB, 0, stream>>>(pk, cursor, row_start, ideg,
                                          xb4, t14, N);
    gather2_lds<<<nbuck, NTB, 0, stream>>>(xb4, t14, pk, cursor, row_start,
                                           ideg, wts, y, N);
}